// Round 4
// baseline (257.210 us; speedup 1.0000x reference)
//
#include <hip/hip_runtime.h>
#include <hip/hip_bf16.h>
#include <math.h>

// (B, Cin, Cout, N, modes) = (16, 128, 128, 8192, 64)
#define NB    16
#define NCIN  128
#define NCOUT 128
#define NN    8192
#define NMOD  64

typedef short bf16x8 __attribute__((ext_vector_type(8)));   // 8 bf16 = 4 VGPRs
typedef short bf16x4 __attribute__((ext_vector_type(4)));   // 8 B
typedef float f32x4  __attribute__((ext_vector_type(4)));   // MFMA acc

#define MFMA16(a, b, c) __builtin_amdgcn_mfma_f32_16x16x32_bf16((a), (b), (c), 0, 0, 0)

__device__ inline unsigned short f2bf_rne(float f) {        // round-to-nearest-even
    unsigned u = __float_as_uint(f);
    u += 0x7FFF + ((u >> 16) & 1);
    return (unsigned short)(u >> 16);
}
__device__ inline short f2bf_trunc(float f) {               // cheap truncation (hot path)
    return (short)(__float_as_uint(f) >> 16);
}

// ---- cvt: x fp32 -> xbt[b][n][i] bf16 (k_out conv-B) and xbn[b][i][n] ------
// block tile: [128 i][32 n]; per-block x working set 16 KB -> L1-resident,
// so the strided 16B reads all hit L1 after first touch. xbt writes are
// 2x256B contiguous segments per instruction.
__global__ __launch_bounds__(256) void k_cvt(const float* __restrict__ x,
                                             unsigned short* __restrict__ xbn,
                                             unsigned short* __restrict__ xbt,
                                             int write_xbn) {
    const int b = blockIdx.x >> 8, nt = blockIdx.x & 255;
    const int i4 = (threadIdx.x & 31) * 4, ng = threadIdx.x >> 5;
    const int n0 = nt * 32 + ng * 4;
    const float* xp = x + ((size_t)b * 128 + i4) * NN + n0;
    float rr[4][4];
    #pragma unroll
    for (int j = 0; j < 4; ++j) {
        float4 r = *(const float4*)(xp + (size_t)j * NN);
        rr[j][0] = r.x; rr[j][1] = r.y; rr[j][2] = r.z; rr[j][3] = r.w;
    }
    #pragma unroll
    for (int c = 0; c < 4; ++c) {                 // transposed: row n, contig i
        short v[4] = { f2bf_trunc(rr[0][c]), f2bf_trunc(rr[1][c]),
                       f2bf_trunc(rr[2][c]), f2bf_trunc(rr[3][c]) };
        *(bf16x4*)(xbt + ((size_t)b * NN + n0 + c) * 128 + i4) = *(bf16x4*)v;
    }
    if (write_xbn) {
        #pragma unroll
        for (int j = 0; j < 4; ++j) {             // straight: row i, contig n
            short v[4] = { f2bf_trunc(rr[j][0]), f2bf_trunc(rr[j][1]),
                           f2bf_trunc(rr[j][2]), f2bf_trunc(rr[j][3]) };
            *(bf16x4*)(xbn + ((size_t)b * 128 + i4 + j) * NN + n0) = *(bf16x4*)v;
        }
    }
}

// ---- prep: trig tables, bf16 conv weight, packed spectral weights -----------
__global__ __launch_bounds__(256) void k_prep(const float* __restrict__ wc,
                                              const float* __restrict__ wsp,
                                              unsigned short* __restrict__ T,
                                              unsigned short* __restrict__ Tt,
                                              unsigned short* __restrict__ Wcb,
                                              unsigned short* __restrict__ Wpk) {
    const float C = 7.66990393943e-4f; // 2*pi/8192
    if (blockIdx.x < 16) {                         // region A: T rows
        int a = blockIdx.x * 256 + threadIdx.x;
        int k = a >> 6, n0 = (a & 63) * 128;
        for (int j8 = 0; j8 < 16; ++j8) {
            short c8[8], s8[8];
            #pragma unroll
            for (int j = 0; j < 8; ++j) {
                int n = n0 + j8 * 8 + j;
                int ph = (k * n) & (NN - 1);
                float sn, cs; __sincosf((float)ph * C, &sn, &cs);
                c8[j] = (short)f2bf_rne(cs);
                s8[j] = (short)f2bf_rne(-sn);
            }
            *(bf16x8*)(T + (size_t)(2 * k) * NN + n0 + j8 * 8)     = *(bf16x8*)c8;
            *(bf16x8*)(T + (size_t)(2 * k + 1) * NN + n0 + j8 * 8) = *(bf16x8*)s8;
        }
    } else if (blockIdx.x < 48) {                  // region B: Tt rows
        int n = (blockIdx.x - 16) * 256 + threadIdx.x;
        for (int k4 = 0; k4 < 16; ++k4) {
            short buf[8];
            #pragma unroll
            for (int j = 0; j < 4; ++j) {
                int k = k4 * 4 + j;
                int ph = (n * k) & (NN - 1);
                float sn, cs; __sincosf((float)ph * C, &sn, &cs);
                buf[2 * j]     = (short)f2bf_rne(cs);
                buf[2 * j + 1] = (short)f2bf_rne(-sn);
            }
            *(bf16x8*)(Tt + (size_t)n * 128 + k4 * 8) = *(bf16x8*)buf;
        }
    } else if (blockIdx.x < 112) {                 // region C: Wc -> bf16
        int j = (blockIdx.x - 48) * 256 + threadIdx.x;
        if (j < NCOUT * NCIN) Wcb[j] = f2bf_rne(wc[j]);
    } else {                                       // region D: pack Wpk
        int g2 = (blockIdx.x - 112) * 256 + threadIdx.x;   // 0..32767
        int k  = g2 & 63;
        int o  = (g2 >> 6) & 127;
        int ch = g2 >> 13;                                  // 0..3
        const float s = (k == 0) ? (1.f / NN) : (2.f / NN);
        const float2* wp = (const float2*)wsp;              // [(i*128+o)*64 + k]
        unsigned short* wre = Wpk + ((size_t)(k * 2 + 0) * 128 + o) * 256;
        unsigned short* wim = Wpk + ((size_t)(k * 2 + 1) * 128 + o) * 256;
        for (int c = ch * 8; c < ch * 8 + 8; ++c) {
            int i0 = 4 * c;
            short re8[8], im8[8];
            #pragma unroll
            for (int t2 = 0; t2 < 4; ++t2) {
                float2 wv = wp[((size_t)(i0 + t2) * 128 + o) * 64 + k];  // lanes: k-contig
                float wr = s * wv.x, wi = s * wv.y;
                re8[2 * t2]     = (short)f2bf_rne(wr);
                re8[2 * t2 + 1] = (short)f2bf_rne(-wi);
                im8[2 * t2]     = (k == 0) ? (short)0 : (short)f2bf_rne(wi);
                im8[2 * t2 + 1] = (k == 0) ? (short)0 : (short)f2bf_rne(wr);
            }
            *(bf16x8*)(wre + c * 8) = *(bf16x8*)re8;
            *(bf16x8*)(wim + c * 8) = *(bf16x8*)im8;
        }
    }
}

// ---- GEMM1: Cpart_t[sp][col][row] = (x * T^T) K-split partials --------------
template<bool BF16SRC>
__global__ __launch_bounds__(256) void k_dftmm(const float* __restrict__ x,
                                               const unsigned short* __restrict__ xbn,
                                               const unsigned short* __restrict__ T,
                                               float* __restrict__ Cpart) {
    const int mt = blockIdx.x & 31, sp = blockIdx.x >> 5;
    const int w = threadIdx.x >> 6, l = threadIdx.x & 63;
    const int l15 = l & 15, q = l >> 4;
    const int colbase = w * 32;
    f32x4 acc[4][2] = {};
    for (int kt = 0; kt < 16; ++kt) {
        const int kb = sp * 512 + kt * 32;
        bf16x8 a[4], bb[2];
        #pragma unroll
        for (int mf = 0; mf < 4; ++mf) {
            const size_t roff = (size_t)(mt * 64 + mf * 16 + l15) * NN + kb + q * 8;
            if (BF16SRC) {
                a[mf] = *(const bf16x8*)(xbn + roff);
            } else {
                const float* ap = x + roff;
                float4 f0 = *(const float4*)ap;
                float4 f1 = *(const float4*)(ap + 4);
                short t8[8] = { f2bf_trunc(f0.x), f2bf_trunc(f0.y), f2bf_trunc(f0.z), f2bf_trunc(f0.w),
                                f2bf_trunc(f1.x), f2bf_trunc(f1.y), f2bf_trunc(f1.z), f2bf_trunc(f1.w) };
                a[mf] = *(bf16x8*)t8;
            }
        }
        #pragma unroll
        for (int nf = 0; nf < 2; ++nf)
            bb[nf] = *(const bf16x8*)(T + (size_t)(colbase + nf * 16 + l15) * NN + kb + q * 8);
        #pragma unroll
        for (int mf = 0; mf < 4; ++mf) {
            acc[mf][0] = MFMA16(a[mf], bb[0], acc[mf][0]);
            acc[mf][1] = MFMA16(a[mf], bb[1], acc[mf][1]);
        }
    }
    #pragma unroll
    for (int mf = 0; mf < 4; ++mf)
        #pragma unroll
        for (int nf = 0; nf < 2; ++nf) {
            int col  = colbase + nf * 16 + l15;
            int row0 = mt * 64 + mf * 16 + q * 4;
            *(f32x4*)(Cpart + (size_t)sp * 262144 + (size_t)col * 2048 + row0) = acc[mf][nf];
        }
}

// ---- reduce 16 K-split partials -> Xf_t[col=2k+p][row=b*128+i] --------------
__global__ __launch_bounds__(256) void k_reduce(const float* __restrict__ Cpart,
                                                float* __restrict__ Xf) {
    int t = blockIdx.x * 256 + threadIdx.x;   // 65536, float4 each
    f32x4 s = {};
    #pragma unroll
    for (int sp = 0; sp < 16; ++sp)
        s += *(const f32x4*)(Cpart + (size_t)sp * 262144 + (size_t)t * 4);
    *(f32x4*)(Xf + (size_t)t * 4) = s;
}

// ---- mix: MFMA complex channel mix -> Aspec[b][o][kk=2k+p] bf16 -------------
__global__ __launch_bounds__(64) void k_mixmm(const float* __restrict__ Xf,
                                              const unsigned short* __restrict__ Wpk,
                                              unsigned short* __restrict__ Aspec) {
    const int k = blockIdx.x >> 2, oq = blockIdx.x & 3;
    const int l = threadIdx.x, l15 = l & 15, q = l >> 4;
    f32x4 ar[2] = {}, ai[2] = {};
    const float* xr = Xf + (size_t)(2 * k) * 2048 + l15 * 128;   // b = l15
    const float* xi = xr + 2048;
    #pragma unroll
    for (int kt = 0; kt < 8; ++kt) {
        int i0 = kt * 16 + q * 4;
        float4 r4 = *(const float4*)(xr + i0);
        float4 i4 = *(const float4*)(xi + i0);
        short a8[8] = { (short)f2bf_rne(r4.x), (short)f2bf_rne(i4.x),
                        (short)f2bf_rne(r4.y), (short)f2bf_rne(i4.y),
                        (short)f2bf_rne(r4.z), (short)f2bf_rne(i4.z),
                        (short)f2bf_rne(r4.w), (short)f2bf_rne(i4.w) };
        bf16x8 a = *(bf16x8*)a8;
        #pragma unroll
        for (int nf = 0; nf < 2; ++nf) {
            int o = oq * 32 + nf * 16 + l15;
            const unsigned short* wb = Wpk + ((size_t)(k * 2) * 128 + o) * 256 + kt * 32 + q * 8;
            bf16x8 bre = *(const bf16x8*)wb;
            bf16x8 bim = *(const bf16x8*)(wb + 32768);
            ar[nf] = MFMA16(a, bre, ar[nf]);
            ai[nf] = MFMA16(a, bim, ai[nf]);
        }
    }
    #pragma unroll
    for (int nf = 0; nf < 2; ++nf) {
        int o = oq * 32 + nf * 16 + l15;
        #pragma unroll
        for (int r = 0; r < 4; ++r) {
            int b = q * 4 + r;
            unsigned v = (unsigned)f2bf_rne(ar[nf][r]) | ((unsigned)f2bf_rne(ai[nf][r]) << 16);
            *(unsigned*)(Aspec + ((size_t)b * 128 + o) * 128 + 2 * k) = v;
        }
    }
}

// ---- GEMM3: out = [Aspec_b | Wcb] x [Tt^T ; xbt_b^T] + bias, GELU -----------
// LDS-free: every fragment is one 16B global load. grid 16 b x 64 n-tiles.
__global__ __launch_bounds__(256) void k_out(const unsigned short* __restrict__ xbt,
                                             const unsigned short* __restrict__ Tt,
                                             const unsigned short* __restrict__ Aspec,
                                             const unsigned short* __restrict__ Wcb,
                                             const float* __restrict__ bias,
                                             float* __restrict__ out) {
    const int b = blockIdx.x >> 6, nt = blockIdx.x & 63;
    const int w = threadIdx.x >> 6, l = threadIdx.x & 63;
    const int l15 = l & 15, q = l >> 4;
    const int nbase = nt * 128 + w * 32;
    f32x4 acc[8][2] = {};
    // spectral half: B from Tt[n][kk], A from Aspec[b][o][kk]
    #pragma unroll
    for (int kt = 0; kt < 4; ++kt) {
        bf16x8 bb[2];
        #pragma unroll
        for (int nf = 0; nf < 2; ++nf) {
            int n = nbase + nf * 16 + l15;
            bb[nf] = *(const bf16x8*)(Tt + (size_t)n * 128 + kt * 32 + q * 8);
        }
        const unsigned short* Ap = Aspec + (size_t)b * 16384 + kt * 32 + q * 8;
        #pragma unroll
        for (int mf = 0; mf < 8; ++mf) {
            bf16x8 a = *(const bf16x8*)(Ap + (size_t)(mf * 16 + l15) * 128);
            acc[mf][0] = MFMA16(a, bb[0], acc[mf][0]);
            acc[mf][1] = MFMA16(a, bb[1], acc[mf][1]);
        }
    }
    // conv half: B from xbt[b][n][i] (contig i!), A from Wcb[o][i]
    #pragma unroll
    for (int kt = 0; kt < 4; ++kt) {
        bf16x8 bb[2];
        #pragma unroll
        for (int nf = 0; nf < 2; ++nf) {
            int n = nbase + nf * 16 + l15;
            bb[nf] = *(const bf16x8*)(xbt + ((size_t)b * NN + n) * 128 + kt * 32 + q * 8);
        }
        const unsigned short* Ap = Wcb + kt * 32 + q * 8;
        #pragma unroll
        for (int mf = 0; mf < 8; ++mf) {
            bf16x8 a = *(const bf16x8*)(Ap + (size_t)(mf * 16 + l15) * 128);
            acc[mf][0] = MFMA16(a, bb[0], acc[mf][0]);
            acc[mf][1] = MFMA16(a, bb[1], acc[mf][1]);
        }
    }
    // epilogue: bias + fast GELU
    #pragma unroll
    for (int mf = 0; mf < 8; ++mf)
        #pragma unroll
        for (int nf = 0; nf < 2; ++nf)
            #pragma unroll
            for (int r = 0; r < 4; ++r) {
                int o = mf * 16 + q * 4 + r;
                int n = nbase + nf * 16 + l15;
                float v = acc[mf][nf][r] + bias[o];
                float u = v * v;
                float p = v * fmaf(0.0713548162f, u, 1.5957691216f);
                float e = __expf(-p);
                float g = v * __builtin_amdgcn_rcpf(1.f + e);
                out[((size_t)(b * 128 + o)) * NN + n] = g;
            }
}

extern "C" void kernel_launch(void* const* d_in, const int* in_sizes, int n_in,
                              void* d_out, int out_size, void* d_ws, size_t ws_size,
                              hipStream_t stream) {
    const float* x    = (const float*)d_in[0];  // [16][128][8192]
    const float* wsp  = (const float*)d_in[1];  // [128][128][64][2]
    const float* wc   = (const float*)d_in[2];  // [128][128]
    const float* bc   = (const float*)d_in[3];  // [128]
    float* out = (float*)d_out;

    unsigned short* T   = (unsigned short*)d_ws;            // 2 MB
    unsigned short* Tt  = T + (size_t)1048576;              // 2 MB
    unsigned short* Wcb = Tt + (size_t)1048576;             // 32 KB
    unsigned short* Asp = Wcb + 16384;                      // 512 KB
    unsigned short* Wpk = Asp + 262144;                     // 16.75 MB
    unsigned short* Xbt = Wpk + (size_t)8388608;            // 32 MB
    float* Cpart = (float*)(Xbt + (size_t)16777216);        // 16 MB
    float* Xf    = Cpart + (size_t)16 * 262144;             // 1 MB  (req ~72.9 MB)
    unsigned short* Xbn = (unsigned short*)(Xf + 262144);   // +32 MB (optional)
    const int use_xbn = (ws_size >= (size_t)107000000) ? 1 : 0;

    k_cvt   <<<4096, 256, 0, stream>>>(x, Xbn, Xbt, use_xbn);
    k_prep  <<<240,  256, 0, stream>>>(wc, wsp, T, Tt, Wcb, Wpk);
    if (use_xbn)
        k_dftmm<true> <<<512, 256, 0, stream>>>(x, Xbn, T, Cpart);
    else
        k_dftmm<false><<<512, 256, 0, stream>>>(x, Xbn, T, Cpart);
    k_reduce<<<256,  256, 0, stream>>>(Cpart, Xf);
    k_mixmm <<<256,  64,  0, stream>>>(Xf, Wpk, Asp);
    k_out   <<<1024, 256, 0, stream>>>(Xbt, Tt, Asp, Wcb, bc, out);
}